// Round 10
// baseline (887.306 us; speedup 1.0000x reference)
//
#include <hip/hip_runtime.h>

// TransformerHead: B=4, S=4096, D_MODEL=1024, D_K=64.  All-bf16 MFMA pipeline.
//   ws layout: xb(32MB) | Wcat(2.25MB) | qk(4MB) | vT(32MB)  ~= 70.4MB
// R1: T2 XOR-swizzle (conflicts 1.09e8 -> 0 on 128B-row read tiles).
// R2: 2-phase pipeline (dbuf, stage-before-compute).
// R3: 128B rows everywhere; swapped QK; reg-staged V.
// R4/R6: v_cvt_pk_bf16_f32 inline asm BANNED (garbage P, bisected). unroll-2 exonerated.
// R5: conflict-free writes: PASS 329us. R7: stats_k dropped, inline denominator: 260.6us.
// R8: VALU diet (prescaled Wq, b64 P-writes, perm-pack): 253.3us; VALUBusy 51->38 but
//     MfmaUtil flat 43 -> pv is LDS-BW bound (~240B/lane/tile ~= 117us of 69TB/s).
// R9: V never touches LDS: PV B-frag = 16 contiguous bytes of vT -> global->reg direct,
//     1-tile-ahead prefetch (named A/B sets, unroll-2, static idx). LDS 56->24KB,
//     ~150B/lane/tile. XCD-swizzled grid (bijective, 512=8x64) so each XCD's resident
//     blocks share a (ck,b) V-chunk: 2x2MB = L2-fit.

#define DEV static __device__ __forceinline__

typedef __attribute__((ext_vector_type(8))) short bf16x8;
typedef __attribute__((ext_vector_type(4))) float f32x4;
typedef __attribute__((ext_vector_type(4))) unsigned short u16x4;
typedef __attribute__((ext_vector_type(8))) unsigned short u16x8;
typedef __attribute__((address_space(1))) void as1_void;
typedef __attribute__((address_space(3))) void as3_void;

DEV unsigned short f2bf(float f) {
  union { float f; unsigned u; } v; v.f = f;
  return (unsigned short)((v.u + 0x7FFFu + ((v.u >> 16) & 1u)) >> 16);
}

// pack bf16(a) (low16) | bf16(b) (high16), round-half-up, via v_perm_b32
DEV unsigned pk_bf16(float a, float b) {
  union { float f; unsigned u; } va, vb;
  va.f = a; vb.f = b;
  return __builtin_amdgcn_perm(vb.u + 0x8000u, va.u + 0x8000u, 0x07060302u);
}

DEV void gload16(const void* g, void* l) {
  __builtin_amdgcn_global_load_lds((as1_void*)g, (as3_void*)l, 16, 0, 0);
}

// 128B-row swizzle (rows of 64 bf16)
DEV int swz(int row, int cb) { return (row << 7) + (cb ^ ((row & 7) << 4)); }

DEV void lgkm_barrier() {  // raw barrier draining lgkm only (keeps vmcnt in flight)
  asm volatile("s_waitcnt lgkmcnt(0)" ::: "memory");
  __builtin_amdgcn_sched_barrier(0);
  __builtin_amdgcn_s_barrier();
  __builtin_amdgcn_sched_barrier(0);
}

// ---------------------------------------------------------------- cast f32->bf16 (+scale)
__global__ __launch_bounds__(256) void cast_bf16_k(const float* __restrict__ in,
                                                   unsigned short* __restrict__ out,
                                                   int n8, float scale) {
  const int stride = gridDim.x * blockDim.x;
  for (int i = blockIdx.x * blockDim.x + threadIdx.x; i < n8; i += stride) {
    const float4* p = (const float4*)in + (size_t)i * 2;
    float4 a = p[0], b = p[1];
    u16x8 r;
    r[0] = f2bf(a.x * scale); r[1] = f2bf(a.y * scale);
    r[2] = f2bf(a.z * scale); r[3] = f2bf(a.w * scale);
    r[4] = f2bf(b.x * scale); r[5] = f2bf(b.y * scale);
    r[6] = f2bf(b.z * scale); r[7] = f2bf(b.w * scale);
    *(u16x8*)(out + (size_t)i * 8) = r;
  }
}

// ---------------------------------------------------------------- QKV projection GEMM
__global__ __launch_bounds__(256, 2) void gemm_qkv_k(
    const unsigned short* __restrict__ xb, const unsigned short* __restrict__ wcat,
    unsigned short* __restrict__ qk, unsigned short* __restrict__ vT) {
  __shared__ __align__(16) unsigned char smem[65536];
  unsigned char* sA = smem;          // 2 x [128][64] bf16, swizzled
  unsigned char* sB = smem + 32768;  // 2 x [128][64] bf16, swizzled
  const int tid = threadIdx.x;
  const int w = tid >> 6, lane = tid & 63, lo = lane & 15, hi = lane >> 4;
  const int wr = w >> 1, wc = w & 1;
  const int bn = blockIdx.x, m0 = blockIdx.y * 128, n0 = bn * 128;
  const char* aBase = (const char*)xb + (size_t)m0 * 2048;
  const char* bBase = (const char*)wcat + (size_t)n0 * 2048;

  const int soff = ((w * 4) << 10) + (lane << 4);
  f32x4 acc[4][4];
  const f32x4 z = {0.f, 0.f, 0.f, 0.f};
#pragma unroll
  for (int mi = 0; mi < 4; ++mi)
#pragma unroll
    for (int ni = 0; ni < 4; ++ni) acc[mi][ni] = z;

#pragma unroll
  for (int r2 = 0; r2 < 4; ++r2) {
    const int off = soff + (r2 << 10);
    const int row = off >> 7;
    const int cbs = (off & 127) ^ ((row & 7) << 4);
    gload16(aBase + (size_t)row * 2048 + cbs, sA + ((w * 4 + r2) << 10));
    gload16(bBase + (size_t)row * 2048 + cbs, sB + ((w * 4 + r2) << 10));
  }
  __syncthreads();

  int cur = 0;
  for (int k0 = 0; k0 < 1024; k0 += 64) {
    if (k0 + 64 < 1024) {
      const int nb = (cur ^ 1) * 16384;
#pragma unroll
      for (int r2 = 0; r2 < 4; ++r2) {
        const int off = soff + (r2 << 10);
        const int row = off >> 7;
        const int cbs = (off & 127) ^ ((row & 7) << 4);
        gload16(aBase + (size_t)row * 2048 + (k0 + 64) * 2 + cbs, sA + nb + ((w * 4 + r2) << 10));
        gload16(bBase + (size_t)row * 2048 + (k0 + 64) * 2 + cbs, sB + nb + ((w * 4 + r2) << 10));
      }
    }
    const int cb0 = cur * 16384;
#pragma unroll
    for (int kk = 0; kk < 2; ++kk) {
      const int cb = kk * 64 + hi * 16;
      bf16x8 af[4], bfv[4];
#pragma unroll
      for (int mi = 0; mi < 4; ++mi)
        af[mi] = *(const bf16x8*)(sA + cb0 + swz(wr * 64 + mi * 16 + lo, cb));
#pragma unroll
      for (int ni = 0; ni < 4; ++ni)
        bfv[ni] = *(const bf16x8*)(sB + cb0 + swz(wc * 64 + ni * 16 + lo, cb));
#pragma unroll
      for (int mi = 0; mi < 4; ++mi)
#pragma unroll
        for (int ni = 0; ni < 4; ++ni)
          acc[mi][ni] = __builtin_amdgcn_mfma_f32_16x16x32_bf16(af[mi], bfv[ni], acc[mi][ni], 0, 0, 0);
    }
    __syncthreads();
    cur ^= 1;
  }

  if (bn == 0) {
#pragma unroll
    for (int mi = 0; mi < 4; ++mi) {
      const int row = m0 + wr * 64 + mi * 16 + hi * 4;
#pragma unroll
      for (int ni = 0; ni < 4; ++ni) {
        const int col = wc * 64 + ni * 16 + lo;
#pragma unroll
        for (int r = 0; r < 4; ++r)
          qk[(size_t)(row + r) * 128 + col] = f2bf(acc[mi][ni][r]);
      }
    }
  } else {
#pragma unroll
    for (int mi = 0; mi < 4; ++mi) {
      const int grow = m0 + wr * 64 + mi * 16 + hi * 4;
      const int b = grow >> 12, s = grow & 4095;
#pragma unroll
      for (int ni = 0; ni < 4; ++ni) {
        const int vcol = (n0 - 128) + wc * 64 + ni * 16 + lo;
        u16x4 pk;
#pragma unroll
        for (int r = 0; r < 4; ++r) pk[r] = f2bf(acc[mi][ni][r]);
        *(u16x4*)(vT + (size_t)(b * 1024 + vcol) * 4096 + s) = pk;
      }
    }
  }
}

// ---------------------------------------------------------------- PV pass (R9)
// Block: 128 q x 256 v, 8 waves, s-tile 32.  K: LDS dbuf (gload16).  V: global->reg,
// 1-tile-ahead prefetch (A/B named sets, unroll-2).  P: LDS (cross-wave).
// LDS: sK 2x[32][64] 8KB | sP [128][128B] 16KB = 24KB.
__global__ __launch_bounds__(512, 4) void pv_k(
    const unsigned short* __restrict__ qk, const unsigned short* __restrict__ vT,
    float* __restrict__ out) {
  __shared__ __align__(16) unsigned char smem[24576];
  unsigned char* sK = smem;         // 2 x [32 s][64 d] bf16 (128B rows, swz128)
  unsigned char* sP = smem + 8192;  // [128 q][128B] rows
  const int tid = threadIdx.x;
  const int w = tid >> 6, lane = tid & 63, lo = lane & 15, hi = lane >> 4;
  const int wr = w >> 2, wc = w & 3;  // PV role: 2x4 wave grid over 128x256

  // XCD-aware bijective swizzle: xcd r gets groups {r, r+8}; group -> (ck,b), member -> qt
  const int flat = blockIdx.x;            // 0..511
  const int xcd = flat & 7, slot = flat >> 3;
  const int group = xcd + ((slot >> 5) << 3);  // 0..15
  const int qt = slot & 31;
  const int ck = group & 3, b = group >> 2;

  const char* qkB = (const char*)qk;
  const char* vTB = (const char*)vT;
  const size_t qrow0 = (size_t)(b * 4096 + qt * 128);
  const f32x4 z = {0.f, 0.f, 0.f, 0.f};

  // Q frags (pre-scaled by 0.125*log2e at cast), direct global -> regs (once).
  const int q = w * 16 + lo;
  bf16x8 qf[2];
#pragma unroll
  for (int kk = 0; kk < 2; ++kk)
    qf[kk] = *(const bf16x8*)(qkB + (qrow0 + q) * 256 + kk * 64 + hi * 16);
  float lsum = 0.f;  // denominator partial for row q

  // K staging (gload16 by waves 0-3, 4KB/tile)
  const int kc = w * 64 + lane;
  const int kRow = kc >> 3;
  const int kCbs = ((kc & 7) << 4) ^ ((kRow & 7) << 4);
  const char* kSrc = qkB + (size_t)(b * 4096 + kRow) * 256 + 128 + kCbs;

  // V base pointers: B-frag lane (lo,hi) = vT[v = wc*64+ni*16+lo][s = t*32 + 8*hi .. +7]
  const char* vBase[4];
#pragma unroll
  for (int ni = 0; ni < 4; ++ni)
    vBase[ni] = vTB + (size_t)(b * 1024 + ck * 256 + wc * 64 + ni * 16 + lo) * 8192 + hi * 16;

  // sP b64 write addresses (quad s=4hi..4hi+3 contiguous; slots (granule)^(q&7))
  const int qx7 = (q & 7) << 4;
  const int aP0 = (q << 7) + ((((hi >> 1) + 0) << 4) ^ qx7) + ((hi & 1) << 3);  // n=0
  const int aP1 = (q << 7) + ((((hi >> 1) + 2) << 4) ^ qx7) + ((hi & 1) << 3);  // n=1

  f32x4 acc[4][4];
#pragma unroll
  for (int mi = 0; mi < 4; ++mi)
#pragma unroll
    for (int ni = 0; ni < 4; ++ni) acc[mi][ni] = z;

  bf16x8 vA[4], vB[4];
  // prologue: V tile 0 -> vA regs; K tile 0 -> sK buf 0
#pragma unroll
  for (int ni = 0; ni < 4; ++ni) vA[ni] = *(const bf16x8*)(vBase[ni]);
  if (w < 4) gload16(kSrc, sK + (w << 10));
  __syncthreads();

#define PV_TILE(T, CURB, VU, VL)                                                      \
  {                                                                                   \
    if ((T) + 1 < 128) {                                                              \
      const size_t toff = (size_t)((T) + 1) * 64;                                     \
      _Pragma("unroll")                                                               \
      for (int ni = 0; ni < 4; ++ni) VL[ni] = *(const bf16x8*)(vBase[ni] + toff);     \
      if (w < 4)                                                                      \
        gload16(kSrc + (size_t)((T) + 1) * 8192, sK + ((CURB) ^ 1) * 4096 + (w << 10)); \
    }                                                                                 \
    f32x4 sv0 = z, sv1 = z;                                                           \
    _Pragma("unroll")                                                                 \
    for (int kk = 0; kk < 2; ++kk) {                                                  \
      bf16x8 kf0 = *(const bf16x8*)(sK + (CURB) * 4096 + swz(lo, kk * 64 + hi * 16)); \
      bf16x8 kf1 = *(const bf16x8*)(sK + (CURB) * 4096 + swz(16 + lo, kk * 64 + hi * 16)); \
      sv0 = __builtin_amdgcn_mfma_f32_16x16x32_bf16(kf0, qf[kk], sv0, 0, 0, 0);       \
      sv1 = __builtin_amdgcn_mfma_f32_16x16x32_bf16(kf1, qf[kk], sv1, 0, 0, 0);       \
    }                                                                                 \
    {                                                                                 \
      const float p0 = __builtin_amdgcn_exp2f(sv0[0]);                                \
      const float p1 = __builtin_amdgcn_exp2f(sv0[1]);                                \
      const float p2 = __builtin_amdgcn_exp2f(sv0[2]);                                \
      const float p3 = __builtin_amdgcn_exp2f(sv0[3]);                                \
      const float p4 = __builtin_amdgcn_exp2f(sv1[0]);                                \
      const float p5 = __builtin_amdgcn_exp2f(sv1[1]);                                \
      const float p6 = __builtin_amdgcn_exp2f(sv1[2]);                                \
      const float p7 = __builtin_amdgcn_exp2f(sv1[3]);                                \
      lsum += ((p0 + p1) + (p2 + p3)) + ((p4 + p5) + (p6 + p7));                      \
      uint2 d0, d1;                                                                   \
      d0.x = pk_bf16(p0, p1); d0.y = pk_bf16(p2, p3);                                 \
      d1.x = pk_bf16(p4, p5); d1.y = pk_bf16(p6, p7);                                 \
      *(uint2*)(sP + aP0) = d0;                                                       \
      *(uint2*)(sP + aP1) = d1;                                                       \
    }                                                                                 \
    lgkm_barrier();                                                                   \
    __builtin_amdgcn_s_setprio(1);                                                    \
    bf16x8 pa[4];                                                                     \
    _Pragma("unroll")                                                                 \
    for (int mi = 0; mi < 4; ++mi)                                                    \
      pa[mi] = *(const bf16x8*)(sP + swz(wr * 64 + mi * 16 + lo, hi * 16));           \
    _Pragma("unroll")                                                                 \
    for (int ni = 0; ni < 4; ++ni) {                                                  \
      _Pragma("unroll")                                                               \
      for (int mi = 0; mi < 4; ++mi)                                                  \
        acc[mi][ni] = __builtin_amdgcn_mfma_f32_16x16x32_bf16(pa[mi], VU[ni], acc[mi][ni], 0, 0, 0); \
    }                                                                                 \
    __builtin_amdgcn_s_setprio(0);                                                    \
    __syncthreads();                                                                  \
  }

  for (int t2 = 0; t2 < 128; t2 += 2) {
    PV_TILE(t2,     0, vA, vB);
    PV_TILE(t2 + 1, 1, vB, vA);
  }
#undef PV_TILE

  // ---- denominator: full row sum = reduce lsum across the 4 hi-groups, broadcast via LDS
  lsum += __shfl_xor(lsum, 16, 64);
  lsum += __shfl_xor(lsum, 32, 64);
  float* lLds = (float*)smem;   // sK region free after final barrier
  if (hi == 0) lLds[q] = lsum;  // q = w*16+lo covers 0..127 across 8 waves
  __syncthreads();

#pragma unroll
  for (int mi = 0; mi < 4; ++mi)
#pragma unroll
    for (int r = 0; r < 4; ++r) {
      const int rloc = wr * 64 + mi * 16 + hi * 4 + r;
      const int grow = (int)qrow0 + rloc;
      const float linv = 1.0f / lLds[rloc];  // same addr for 16 lanes -> broadcast
#pragma unroll
      for (int ni = 0; ni < 4; ++ni) {
        const int col = ck * 256 + wc * 64 + ni * 16 + lo;
        out[(size_t)grow * 1024 + col] = acc[mi][ni][r] * linv;
      }
    }
}

// ---------------------------------------------------------------- launch
extern "C" void kernel_launch(void* const* d_in, const int* in_sizes, int n_in,
                              void* d_out, int out_size, void* d_ws, size_t ws_size,
                              hipStream_t stream) {
  const float* x  = (const float*)d_in[0];
  const float* Wq = (const float*)d_in[1];
  const float* Wk = (const float*)d_in[2];
  const float* Wv = (const float*)d_in[3];

  char* ws = (char*)d_ws;
  unsigned short* xb    = (unsigned short*)(ws);               // 33,554,432 B
  unsigned short* wcat  = (unsigned short*)(ws + 33554432);    //  2,359,296 B
  unsigned short* qk    = (unsigned short*)(ws + 35913728);    //  4,194,304 B
  unsigned short* vT    = (unsigned short*)(ws + 40108032);    // 33,554,432 B

  const float SCALE_Q = 0.125f * 1.4426950408889634f;  // fold softmax scale+log2e into Wq

  cast_bf16_k<<<2048, 256, 0, stream>>>(x, xb, 2097152, 1.0f);
  cast_bf16_k<<<32, 256, 0, stream>>>(Wq, wcat, 8192, SCALE_Q);
  cast_bf16_k<<<32, 256, 0, stream>>>(Wk, wcat + 65536, 8192, 1.0f);
  cast_bf16_k<<<512, 256, 0, stream>>>(Wv, wcat + 131072, 131072, 1.0f);

  gemm_qkv_k<<<dim3(9, 128), 256, 0, stream>>>(xb, wcat, qk, vT);
  pv_k<<<512, 512, 0, stream>>>(qk, vT, (float*)d_out);
}

// Round 11
// 249.271 us; speedup vs baseline: 3.5596x; 3.5596x over previous
//
#include <hip/hip_runtime.h>

// TransformerHead: B=4, S=4096, D_MODEL=1024, D_K=64.  All-bf16 MFMA pipeline.
//   ws layout: xb(32MB) | Wcat(2.25MB) | qk(4MB) | vT(32MB)  ~= 70.4MB
// R1: T2 XOR-swizzle (conflicts 1.09e8 -> 0 on 128B-row read tiles).
// R2: 2-phase pipeline (dbuf, stage-before-compute).
// R3: 128B rows everywhere; swapped QK; reg-staged V.
// R4/R6: v_cvt_pk_bf16_f32 inline asm BANNED (garbage P, bisected).
// R5: conflict-free writes: PASS 329us. R7: stats_k dropped, inline denominator: 260.6us.
// R8: VALU diet (prescaled Wq, b64 P-writes, perm-pack): 253.3us, pv 180.5us,
//     MfmaUtil 43 / VALUBusy 38, ~810 TF effective in pv (near 2-barrier ~900 ceiling).
// R9: FAILED perf (873us pv): V global->reg = 16B stride-8192 gathers -> FETCH 1.2GB.
//     RULE: V transport must be block-cooperative+coalesced; per-lane strided global
//     gathers banned.
// R10: revert pv to exact R8; merge 4 cast launches into one kernel (saves launch gaps).

#define DEV static __device__ __forceinline__

typedef __attribute__((ext_vector_type(8))) short bf16x8;
typedef __attribute__((ext_vector_type(4))) float f32x4;
typedef __attribute__((ext_vector_type(4))) unsigned short u16x4;
typedef __attribute__((ext_vector_type(8))) unsigned short u16x8;
typedef __attribute__((address_space(1))) void as1_void;
typedef __attribute__((address_space(3))) void as3_void;

DEV unsigned short f2bf(float f) {
  union { float f; unsigned u; } v; v.f = f;
  return (unsigned short)((v.u + 0x7FFFu + ((v.u >> 16) & 1u)) >> 16);
}

// pack bf16(a) (low16) | bf16(b) (high16), round-half-up, via v_perm_b32
DEV unsigned pk_bf16(float a, float b) {
  union { float f; unsigned u; } va, vb;
  va.f = a; vb.f = b;
  return __builtin_amdgcn_perm(vb.u + 0x8000u, va.u + 0x8000u, 0x07060302u);
}

DEV void gload16(const void* g, void* l) {
  __builtin_amdgcn_global_load_lds((as1_void*)g, (as3_void*)l, 16, 0, 0);
}

// 128B-row swizzle (rows of 64 bf16)
DEV int swz(int row, int cb) { return (row << 7) + (cb ^ ((row & 7) << 4)); }

DEV void lgkm_barrier() {  // raw barrier draining lgkm only (keeps vmcnt in flight)
  asm volatile("s_waitcnt lgkmcnt(0)" ::: "memory");
  __builtin_amdgcn_sched_barrier(0);
  __builtin_amdgcn_s_barrier();
  __builtin_amdgcn_sched_barrier(0);
}

// ---------------------------------------------------------------- fused cast f32->bf16
// regions (n8 units): [0,2097152) x->xb | [..,+8192) Wq->wcat (SCALE_Q) |
//                     [..,+8192) Wk->wcat+65536 | [..,+131072) Wv->wcat+131072
__global__ __launch_bounds__(256) void cast_all_k(
    const float* __restrict__ x, const float* __restrict__ wq,
    const float* __restrict__ wk, const float* __restrict__ wv,
    unsigned short* __restrict__ xb, unsigned short* __restrict__ wcat, float sq) {
  const int stride = gridDim.x * blockDim.x;
  for (int i = blockIdx.x * blockDim.x + threadIdx.x; i < 2244608; i += stride) {
    const float* src; unsigned short* dst; float scale; int j;
    if (i < 2097152)      { src = x;  dst = xb;            scale = 1.f; j = i; }
    else if (i < 2105344) { src = wq; dst = wcat;          scale = sq;  j = i - 2097152; }
    else if (i < 2113536) { src = wk; dst = wcat + 65536;  scale = 1.f; j = i - 2105344; }
    else                  { src = wv; dst = wcat + 131072; scale = 1.f; j = i - 2113536; }
    const float4* p = (const float4*)src + (size_t)j * 2;
    float4 a = p[0], b = p[1];
    u16x8 r;
    r[0] = f2bf(a.x * scale); r[1] = f2bf(a.y * scale);
    r[2] = f2bf(a.z * scale); r[3] = f2bf(a.w * scale);
    r[4] = f2bf(b.x * scale); r[5] = f2bf(b.y * scale);
    r[6] = f2bf(b.z * scale); r[7] = f2bf(b.w * scale);
    *(u16x8*)(dst + (size_t)j * 8) = r;
  }
}

// ---------------------------------------------------------------- QKV projection GEMM
__global__ __launch_bounds__(256, 2) void gemm_qkv_k(
    const unsigned short* __restrict__ xb, const unsigned short* __restrict__ wcat,
    unsigned short* __restrict__ qk, unsigned short* __restrict__ vT) {
  __shared__ __align__(16) unsigned char smem[65536];
  unsigned char* sA = smem;          // 2 x [128][64] bf16, swizzled
  unsigned char* sB = smem + 32768;  // 2 x [128][64] bf16, swizzled
  const int tid = threadIdx.x;
  const int w = tid >> 6, lane = tid & 63, lo = lane & 15, hi = lane >> 4;
  const int wr = w >> 1, wc = w & 1;
  const int bn = blockIdx.x, m0 = blockIdx.y * 128, n0 = bn * 128;
  const char* aBase = (const char*)xb + (size_t)m0 * 2048;
  const char* bBase = (const char*)wcat + (size_t)n0 * 2048;

  const int soff = ((w * 4) << 10) + (lane << 4);
  f32x4 acc[4][4];
  const f32x4 z = {0.f, 0.f, 0.f, 0.f};
#pragma unroll
  for (int mi = 0; mi < 4; ++mi)
#pragma unroll
    for (int ni = 0; ni < 4; ++ni) acc[mi][ni] = z;

#pragma unroll
  for (int r2 = 0; r2 < 4; ++r2) {
    const int off = soff + (r2 << 10);
    const int row = off >> 7;
    const int cbs = (off & 127) ^ ((row & 7) << 4);
    gload16(aBase + (size_t)row * 2048 + cbs, sA + ((w * 4 + r2) << 10));
    gload16(bBase + (size_t)row * 2048 + cbs, sB + ((w * 4 + r2) << 10));
  }
  __syncthreads();

  int cur = 0;
  for (int k0 = 0; k0 < 1024; k0 += 64) {
    if (k0 + 64 < 1024) {
      const int nb = (cur ^ 1) * 16384;
#pragma unroll
      for (int r2 = 0; r2 < 4; ++r2) {
        const int off = soff + (r2 << 10);
        const int row = off >> 7;
        const int cbs = (off & 127) ^ ((row & 7) << 4);
        gload16(aBase + (size_t)row * 2048 + (k0 + 64) * 2 + cbs, sA + nb + ((w * 4 + r2) << 10));
        gload16(bBase + (size_t)row * 2048 + (k0 + 64) * 2 + cbs, sB + nb + ((w * 4 + r2) << 10));
      }
    }
    const int cb0 = cur * 16384;
#pragma unroll
    for (int kk = 0; kk < 2; ++kk) {
      const int cb = kk * 64 + hi * 16;
      bf16x8 af[4], bfv[4];
#pragma unroll
      for (int mi = 0; mi < 4; ++mi)
        af[mi] = *(const bf16x8*)(sA + cb0 + swz(wr * 64 + mi * 16 + lo, cb));
#pragma unroll
      for (int ni = 0; ni < 4; ++ni)
        bfv[ni] = *(const bf16x8*)(sB + cb0 + swz(wc * 64 + ni * 16 + lo, cb));
#pragma unroll
      for (int mi = 0; mi < 4; ++mi)
#pragma unroll
        for (int ni = 0; ni < 4; ++ni)
          acc[mi][ni] = __builtin_amdgcn_mfma_f32_16x16x32_bf16(af[mi], bfv[ni], acc[mi][ni], 0, 0, 0);
    }
    __syncthreads();
    cur ^= 1;
  }

  if (bn == 0) {
#pragma unroll
    for (int mi = 0; mi < 4; ++mi) {
      const int row = m0 + wr * 64 + mi * 16 + hi * 4;
#pragma unroll
      for (int ni = 0; ni < 4; ++ni) {
        const int col = wc * 64 + ni * 16 + lo;
#pragma unroll
        for (int r = 0; r < 4; ++r)
          qk[(size_t)(row + r) * 128 + col] = f2bf(acc[mi][ni][r]);
      }
    }
  } else {
#pragma unroll
    for (int mi = 0; mi < 4; ++mi) {
      const int grow = m0 + wr * 64 + mi * 16 + hi * 4;
      const int b = grow >> 12, s = grow & 4095;
#pragma unroll
      for (int ni = 0; ni < 4; ++ni) {
        const int vcol = (n0 - 128) + wc * 64 + ni * 16 + lo;
        u16x4 pk;
#pragma unroll
        for (int r = 0; r < 4; ++r) pk[r] = f2bf(acc[mi][ni][r]);
        *(u16x4*)(vT + (size_t)(b * 1024 + vcol) * 4096 + s) = pk;
      }
    }
  }
}

// ---------------------------------------------------------------- PV pass (exact R8)
// Block: 128 q x 256 v, 8 waves, s-tile 32, dbuf K+V (1-deep V reg stage).
// LDS: sK 2x[32][64] 8KB | sV [256][64] paired halves 32KB | sP [128][128B] 16KB = 56KB.
__global__ __launch_bounds__(512, 4) void pv_k(
    const unsigned short* __restrict__ qk, const unsigned short* __restrict__ vT,
    float* __restrict__ out) {
  __shared__ __align__(16) unsigned char smem[57344];
  unsigned char* sK = smem;          // 2 x [32 s][64 d] bf16 (128B rows, swz128)
  unsigned char* sV = smem + 8192;   // [256 v][64] bf16: col-half per buffer, XOR swz
  unsigned char* sP = smem + 40960;  // [128 q][128B] rows
  const int tid = threadIdx.x;
  const int w = tid >> 6, lane = tid & 63, lo = lane & 15, hi = lane >> 4;
  const int wr = w >> 2, wc = w & 3;  // PV role: 2x4 wave grid over 128x256
  const int ck = blockIdx.x, qt = blockIdx.y, b = blockIdx.z;
  const char* qkB = (const char*)qk;
  const char* vTB = (const char*)vT;
  const size_t qrow0 = (size_t)(b * 4096 + qt * 128);
  const f32x4 z = {0.f, 0.f, 0.f, 0.f};

  // Q frags (pre-scaled by 0.125*log2e at cast), direct global -> regs (once).
  const int q = w * 16 + lo;
  bf16x8 qf[2];
#pragma unroll
  for (int kk = 0; kk < 2; ++kk)
    qf[kk] = *(const bf16x8*)(qkB + (qrow0 + q) * 256 + kk * 64 + hi * 16);
  float lsum = 0.f;  // denominator partial for row q

  // K staging (gload16 by waves 0-3, 4KB/tile)
  const int kc = w * 64 + lane;
  const int kRow = kc >> 3;
  const int kCbs = ((kc & 7) << 4) ^ ((kRow & 7) << 4);
  const char* kSrc = qkB + (size_t)(b * 4096 + kRow) * 256 + 128 + kCbs;

  // V staging, conflict-free chunk map: 8-lane group = rows {r, r+4} x g0..3
  const int g = lane & 3, dr = (lane >> 2) & 1, qq = lane >> 3;
  const int rr = (qq & 3) + ((qq >> 2) << 3) + (dr << 2);  // 0..15, bijective over (qq,dr)
  const int vRow0 = w * 16 + rr, vRow1 = vRow0 + 128;      // vRow1&7 == vRow0&7
  const char* vSrc0 = vTB + (size_t)(b * 1024 + ck * 256 + vRow0) * 8192 + g * 16;
  const char* vSrc1 = vTB + (size_t)(b * 1024 + ck * 256 + vRow1) * 8192 + g * 16;
  unsigned char* vDst0 = sV + vRow0 * 128;
  unsigned char* vDst1 = sV + vRow1 * 128;
  const int vX = g << 4, vR = (vRow0 & 7) << 4;  // byte = (buf*64 + vX) ^ vR

  // sP b64 write addresses: quad (s=4hi..4hi+3) is 8 contiguous bytes in one granule.
  const int qx7 = (q & 7) << 4;
  const int aP0 = (q << 7) + ((((hi >> 1) + 0) << 4) ^ qx7) + ((hi & 1) << 3);  // n=0
  const int aP1 = (q << 7) + ((((hi >> 1) + 2) << 4) ^ qx7) + ((hi & 1) << 3);  // n=1

  f32x4 acc[4][4];
#pragma unroll
  for (int mi = 0; mi < 4; ++mi)
#pragma unroll
    for (int ni = 0; ni < 4; ++ni) acc[mi][ni] = z;

  // prologue: stage tile 0 into buf 0
  {
    float4 v0 = *(const float4*)(vSrc0);
    float4 v1 = *(const float4*)(vSrc1);
    if (w < 4) gload16(kSrc, sK + (w << 10));
    *(float4*)(vDst0 + (vX ^ vR)) = v0;
    *(float4*)(vDst1 + (vX ^ vR)) = v1;
  }
  __syncthreads();

  int cur = 0;
  for (int t = 0; t < 128; ++t) {
    float4 nv0, nv1;
    if (t < 127) {  // issue next-tile loads (write deferred past lgkm barrier)
      nv0 = *(const float4*)(vSrc0 + (size_t)(t + 1) * 64);
      nv1 = *(const float4*)(vSrc1 + (size_t)(t + 1) * 64);
      if (w < 4) gload16(kSrc + (size_t)(t + 1) * 8192, sK + (cur ^ 1) * 4096 + (w << 10));
    }
    // ---- swapped QK: D[s][q], lane owns q = lo (scores pre-scaled)
    f32x4 sv0 = z, sv1 = z;
#pragma unroll
    for (int kk = 0; kk < 2; ++kk) {
      bf16x8 kf0 = *(const bf16x8*)(sK + cur * 4096 + swz(lo, kk * 64 + hi * 16));
      bf16x8 kf1 = *(const bf16x8*)(sK + cur * 4096 + swz(16 + lo, kk * 64 + hi * 16));
      sv0 = __builtin_amdgcn_mfma_f32_16x16x32_bf16(kf0, qf[kk], sv0, 0, 0, 0);
      sv1 = __builtin_amdgcn_mfma_f32_16x16x32_bf16(kf1, qf[kk], sv1, 0, 0, 0);
    }
    // ---- exp2 (unnormalized) -> l partial + 2x b64 P writes (s = n*16 + 4*hi + r)
    {
      const float p0 = __builtin_amdgcn_exp2f(sv0[0]);
      const float p1 = __builtin_amdgcn_exp2f(sv0[1]);
      const float p2 = __builtin_amdgcn_exp2f(sv0[2]);
      const float p3 = __builtin_amdgcn_exp2f(sv0[3]);
      const float p4 = __builtin_amdgcn_exp2f(sv1[0]);
      const float p5 = __builtin_amdgcn_exp2f(sv1[1]);
      const float p6 = __builtin_amdgcn_exp2f(sv1[2]);
      const float p7 = __builtin_amdgcn_exp2f(sv1[3]);
      lsum += ((p0 + p1) + (p2 + p3)) + ((p4 + p5) + (p6 + p7));
      uint2 d0, d1;
      d0.x = pk_bf16(p0, p1); d0.y = pk_bf16(p2, p3);
      d1.x = pk_bf16(p4, p5); d1.y = pk_bf16(p6, p7);
      *(uint2*)(sP + aP0) = d0;
      *(uint2*)(sP + aP1) = d1;
    }
    lgkm_barrier();  // P visible to all waves; vmcnt (K prefetch) stays in flight
    if (t < 127) {   // V ds_writes into buf^1 (read only after next __syncthreads)
      *(float4*)(vDst0 + ((((cur ^ 1) << 6) + vX) ^ vR)) = nv0;
      *(float4*)(vDst1 + ((((cur ^ 1) << 6) + vX) ^ vR)) = nv1;
    }
    // ---- PV: wave (wr,wc): rows wr*64..+64, cols wc*64..+64, k = 32
    __builtin_amdgcn_s_setprio(1);
    bf16x8 pa[4];
#pragma unroll
    for (int mi = 0; mi < 4; ++mi)
      pa[mi] = *(const bf16x8*)(sP + swz(wr * 64 + mi * 16 + lo, hi * 16));
#pragma unroll
    for (int ni = 0; ni < 4; ++ni) {
      bf16x8 vf = *(const bf16x8*)(sV + swz(wc * 64 + ni * 16 + lo, (cur << 6) + hi * 16));
#pragma unroll
      for (int mi = 0; mi < 4; ++mi)
        acc[mi][ni] = __builtin_amdgcn_mfma_f32_16x16x32_bf16(pa[mi], vf, acc[mi][ni], 0, 0, 0);
    }
    __builtin_amdgcn_s_setprio(0);
    __syncthreads();  // drains vmcnt (K stage) + lgkm (V writes); bufs swap
    cur ^= 1;
  }

  // ---- denominator: full row sum = reduce lsum across the 4 hi-groups, broadcast via LDS
  lsum += __shfl_xor(lsum, 16, 64);
  lsum += __shfl_xor(lsum, 32, 64);
  float* lLds = (float*)smem;   // sK region free after final barrier
  if (hi == 0) lLds[q] = lsum;  // q = w*16+lo covers 0..127 across 8 waves
  __syncthreads();

#pragma unroll
  for (int mi = 0; mi < 4; ++mi)
#pragma unroll
    for (int r = 0; r < 4; ++r) {
      const int rloc = wr * 64 + mi * 16 + hi * 4 + r;
      const int grow = (int)qrow0 + rloc;
      const float linv = 1.0f / lLds[rloc];  // same addr for 16 lanes -> broadcast
#pragma unroll
      for (int ni = 0; ni < 4; ++ni) {
        const int col = ck * 256 + wc * 64 + ni * 16 + lo;
        out[(size_t)grow * 1024 + col] = acc[mi][ni][r] * linv;
      }
    }
}

// ---------------------------------------------------------------- launch
extern "C" void kernel_launch(void* const* d_in, const int* in_sizes, int n_in,
                              void* d_out, int out_size, void* d_ws, size_t ws_size,
                              hipStream_t stream) {
  const float* x  = (const float*)d_in[0];
  const float* Wq = (const float*)d_in[1];
  const float* Wk = (const float*)d_in[2];
  const float* Wv = (const float*)d_in[3];

  char* ws = (char*)d_ws;
  unsigned short* xb    = (unsigned short*)(ws);               // 33,554,432 B
  unsigned short* wcat  = (unsigned short*)(ws + 33554432);    //  2,359,296 B
  unsigned short* qk    = (unsigned short*)(ws + 35913728);    //  4,194,304 B
  unsigned short* vT    = (unsigned short*)(ws + 40108032);    // 33,554,432 B

  const float SCALE_Q = 0.125f * 1.4426950408889634f;  // fold softmax scale+log2e into Wq

  cast_all_k<<<2048, 256, 0, stream>>>(x, Wq, Wk, Wv, xb, wcat, SCALE_Q);
  gemm_qkv_k<<<dim3(9, 128), 256, 0, stream>>>(xb, wcat, qk, vT);
  pv_k<<<dim3(4, 32, 4), 512, 0, stream>>>(qk, vT, (float*)d_out);
}

// Round 12
// 240.176 us; speedup vs baseline: 3.6944x; 1.0379x over previous
//
#include <hip/hip_runtime.h>

// TransformerHead: B=4, S=4096, D_MODEL=1024, D_K=64.  All-bf16 MFMA pipeline.
//   ws layout: xb(32MB) | Wcat(2.25MB) | qk(4MB) | vT(32MB)  ~= 70.4MB
// R1: T2 XOR-swizzle (conflicts 1.09e8 -> 0 on 128B-row read tiles).
// R3: swapped QK (lane owns q-row); reg-staged V.  R4/R6: cvt_pk asm BANNED.
// R5: conflict-free writes: 329us.  R7: stats_k dropped, inline denominator: 260.6us.
// R8: VALU diet (prescaled Wq, b64 P-writes, perm-pack): 253.3us, pv 179.5us @ 811 TF
//     (~90% of the 2-barrier structure ceiling).
// R9: FAILED perf: per-lane strided V gathers -> FETCH 1.2GB. BANNED.
// R10: revert pv to R8 + fused cast: 249.3us.
// R11: s-tile 64 restructure (halves barriers per s-element):
//      - V via gload16 into a SINGLE 32KB buffer (rule #21 pre-swizzled source,
//        coalesced within 128B row segments); issued AFTER end-of-tile sync
//        (all reads done), landed at next mid-barrier via counted vmcnt(1) (T4).
//      - K-tile 64x64 dbuf, all 8 waves staging.  sK/sV/sP all full 128B rows, swz128.
//      - mid barrier = s_waitcnt vmcnt(1) lgkmcnt(0) + s_barrier (rule #18 fences).
//      Barriers per 64 s: 4 -> 2.  LDS 64KB, 2 blocks/CU.

#define DEV static __device__ __forceinline__

typedef __attribute__((ext_vector_type(8))) short bf16x8;
typedef __attribute__((ext_vector_type(4))) float f32x4;
typedef __attribute__((ext_vector_type(4))) unsigned short u16x4;
typedef __attribute__((ext_vector_type(8))) unsigned short u16x8;
typedef __attribute__((address_space(1))) void as1_void;
typedef __attribute__((address_space(3))) void as3_void;

DEV unsigned short f2bf(float f) {
  union { float f; unsigned u; } v; v.f = f;
  return (unsigned short)((v.u + 0x7FFFu + ((v.u >> 16) & 1u)) >> 16);
}

// pack bf16(a) (low16) | bf16(b) (high16), round-half-up, via v_perm_b32
DEV unsigned pk_bf16(float a, float b) {
  union { float f; unsigned u; } va, vb;
  va.f = a; vb.f = b;
  return __builtin_amdgcn_perm(vb.u + 0x8000u, va.u + 0x8000u, 0x07060302u);
}

DEV void gload16(const void* g, void* l) {
  __builtin_amdgcn_global_load_lds((as1_void*)g, (as3_void*)l, 16, 0, 0);
}

// 128B-row swizzle (rows of 64 bf16)
DEV int swz(int row, int cb) { return (row << 7) + (cb ^ ((row & 7) << 4)); }

// ---------------------------------------------------------------- fused cast f32->bf16
__global__ __launch_bounds__(256) void cast_all_k(
    const float* __restrict__ x, const float* __restrict__ wq,
    const float* __restrict__ wk, const float* __restrict__ wv,
    unsigned short* __restrict__ xb, unsigned short* __restrict__ wcat, float sq) {
  const int stride = gridDim.x * blockDim.x;
  for (int i = blockIdx.x * blockDim.x + threadIdx.x; i < 2244608; i += stride) {
    const float* src; unsigned short* dst; float scale; int j;
    if (i < 2097152)      { src = x;  dst = xb;            scale = 1.f; j = i; }
    else if (i < 2105344) { src = wq; dst = wcat;          scale = sq;  j = i - 2097152; }
    else if (i < 2113536) { src = wk; dst = wcat + 65536;  scale = 1.f; j = i - 2105344; }
    else                  { src = wv; dst = wcat + 131072; scale = 1.f; j = i - 2113536; }
    const float4* p = (const float4*)src + (size_t)j * 2;
    float4 a = p[0], b = p[1];
    u16x8 r;
    r[0] = f2bf(a.x * scale); r[1] = f2bf(a.y * scale);
    r[2] = f2bf(a.z * scale); r[3] = f2bf(a.w * scale);
    r[4] = f2bf(b.x * scale); r[5] = f2bf(b.y * scale);
    r[6] = f2bf(b.z * scale); r[7] = f2bf(b.w * scale);
    *(u16x8*)(dst + (size_t)j * 8) = r;
  }
}

// ---------------------------------------------------------------- QKV projection GEMM (R10 exact)
__global__ __launch_bounds__(256, 2) void gemm_qkv_k(
    const unsigned short* __restrict__ xb, const unsigned short* __restrict__ wcat,
    unsigned short* __restrict__ qk, unsigned short* __restrict__ vT) {
  __shared__ __align__(16) unsigned char smem[65536];
  unsigned char* sA = smem;          // 2 x [128][64] bf16, swizzled
  unsigned char* sB = smem + 32768;  // 2 x [128][64] bf16, swizzled
  const int tid = threadIdx.x;
  const int w = tid >> 6, lane = tid & 63, lo = lane & 15, hi = lane >> 4;
  const int wr = w >> 1, wc = w & 1;
  const int bn = blockIdx.x, m0 = blockIdx.y * 128, n0 = bn * 128;
  const char* aBase = (const char*)xb + (size_t)m0 * 2048;
  const char* bBase = (const char*)wcat + (size_t)n0 * 2048;

  const int soff = ((w * 4) << 10) + (lane << 4);
  f32x4 acc[4][4];
  const f32x4 z = {0.f, 0.f, 0.f, 0.f};
#pragma unroll
  for (int mi = 0; mi < 4; ++mi)
#pragma unroll
    for (int ni = 0; ni < 4; ++ni) acc[mi][ni] = z;

#pragma unroll
  for (int r2 = 0; r2 < 4; ++r2) {
    const int off = soff + (r2 << 10);
    const int row = off >> 7;
    const int cbs = (off & 127) ^ ((row & 7) << 4);
    gload16(aBase + (size_t)row * 2048 + cbs, sA + ((w * 4 + r2) << 10));
    gload16(bBase + (size_t)row * 2048 + cbs, sB + ((w * 4 + r2) << 10));
  }
  __syncthreads();

  int cur = 0;
  for (int k0 = 0; k0 < 1024; k0 += 64) {
    if (k0 + 64 < 1024) {
      const int nb = (cur ^ 1) * 16384;
#pragma unroll
      for (int r2 = 0; r2 < 4; ++r2) {
        const int off = soff + (r2 << 10);
        const int row = off >> 7;
        const int cbs = (off & 127) ^ ((row & 7) << 4);
        gload16(aBase + (size_t)row * 2048 + (k0 + 64) * 2 + cbs, sA + nb + ((w * 4 + r2) << 10));
        gload16(bBase + (size_t)row * 2048 + (k0 + 64) * 2 + cbs, sB + nb + ((w * 4 + r2) << 10));
      }
    }
    const int cb0 = cur * 16384;
#pragma unroll
    for (int kk = 0; kk < 2; ++kk) {
      const int cb = kk * 64 + hi * 16;
      bf16x8 af[4], bfv[4];
#pragma unroll
      for (int mi = 0; mi < 4; ++mi)
        af[mi] = *(const bf16x8*)(sA + cb0 + swz(wr * 64 + mi * 16 + lo, cb));
#pragma unroll
      for (int ni = 0; ni < 4; ++ni)
        bfv[ni] = *(const bf16x8*)(sB + cb0 + swz(wc * 64 + ni * 16 + lo, cb));
#pragma unroll
      for (int mi = 0; mi < 4; ++mi)
#pragma unroll
        for (int ni = 0; ni < 4; ++ni)
          acc[mi][ni] = __builtin_amdgcn_mfma_f32_16x16x32_bf16(af[mi], bfv[ni], acc[mi][ni], 0, 0, 0);
    }
    __syncthreads();
    cur ^= 1;
  }

  if (bn == 0) {
#pragma unroll
    for (int mi = 0; mi < 4; ++mi) {
      const int row = m0 + wr * 64 + mi * 16 + hi * 4;
#pragma unroll
      for (int ni = 0; ni < 4; ++ni) {
        const int col = wc * 64 + ni * 16 + lo;
#pragma unroll
        for (int r = 0; r < 4; ++r)
          qk[(size_t)(row + r) * 128 + col] = f2bf(acc[mi][ni][r]);
      }
    }
  } else {
#pragma unroll
    for (int mi = 0; mi < 4; ++mi) {
      const int grow = m0 + wr * 64 + mi * 16 + hi * 4;
      const int b = grow >> 12, s = grow & 4095;
#pragma unroll
      for (int ni = 0; ni < 4; ++ni) {
        const int vcol = (n0 - 128) + wc * 64 + ni * 16 + lo;
        u16x4 pk;
#pragma unroll
        for (int r = 0; r < 4; ++r) pk[r] = f2bf(acc[mi][ni][r]);
        *(u16x4*)(vT + (size_t)(b * 1024 + vcol) * 4096 + s) = pk;
      }
    }
  }
}

// ---------------------------------------------------------------- PV pass (R11: s-tile 64)
// Block: 128 q x 256 v, 8 waves.  LDS: sK 2x[64s][64d] 16KB | sV [256v][64s] 32KB single |
// sP [128q][64s] 16KB = 64KB.  Per tile: issue K(t+1) -> QK(8 MFMA) -> exp(16)+P(4xb64)
// -> vmcnt(1)+lgkm barrier (V landed, K prefetch in flight) -> PV(32 MFMA) -> syncthreads
// -> issue V(t+1) gloads (all sV reads done).
__global__ __launch_bounds__(512, 4) void pv_k(
    const unsigned short* __restrict__ qk, const unsigned short* __restrict__ vT,
    float* __restrict__ out) {
  __shared__ __align__(16) unsigned char smem[65536];
  unsigned char* sK = smem;          // 2 x [64][128B], swz128
  unsigned char* sV = smem + 16384;  // [256][128B] single buf, swz128
  unsigned char* sP = smem + 49152;  // [128][128B], swz128
  const int tid = threadIdx.x;
  const int w = tid >> 6, lane = tid & 63, lo = lane & 15, hi = lane >> 4;
  const int wr = w >> 2, wc = w & 3;  // PV role: 2x4 wave grid over 128x256
  const int ck = blockIdx.x, qt = blockIdx.y, b = blockIdx.z;
  const char* qkB = (const char*)qk;
  const char* vTB = (const char*)vT;
  const size_t qrow0 = (size_t)(b * 4096 + qt * 128);
  const f32x4 z = {0.f, 0.f, 0.f, 0.f};

  // Q frags (pre-scaled by 0.125*log2e at cast), direct global -> regs (once).
  const int q = w * 16 + lo;
  bf16x8 qf[2];
#pragma unroll
  for (int kk = 0; kk < 2; ++kk)
    qf[kk] = *(const bf16x8*)(qkB + (qrow0 + q) * 256 + kk * 64 + hi * 16);
  float lsum = 0.f;

  // K staging: tile [64s][64d]=8KB, all 8 waves 1 issue each; chunk kc: row=kc>>3, g=kc&7
  const int kc = w * 64 + lane;
  const int kRow = kc >> 3, kG = kc & 7;
  const char* kSrc = qkB + (size_t)(b * 4096 + kRow) * 256 + 128 + ((kG ^ (kRow & 7)) << 4);
  unsigned char* kDst = sK + (kc << 4);  // + buf*8192

  // V staging: tile [256v][64s]=32KB, 4 issues/lane; chunk c=tid+j*512: row=c>>3, g=c&7
  // pre-swizzled source col (rule #21); LDS dest linear.
  const char* vSrcJ[4];
#pragma unroll
  for (int j = 0; j < 4; ++j) {
    const int c = tid + j * 512;
    const int row = c >> 3, g = c & 7;
    vSrcJ[j] = vTB + (size_t)(b * 1024 + ck * 256 + row) * 8192 + ((g ^ (row & 7)) << 4);
  }

  // sP b64 write addrs: n=0..3, s=n*16+4hi+r -> granule 2n+(hi>>1), slot ^(q&7)
  const int qx7 = (q & 7) << 4;
  const int aP0 = (q << 7) + (((0 + (hi >> 1)) << 4) ^ qx7) + ((hi & 1) << 3);
  const int aP1 = (q << 7) + (((2 + (hi >> 1)) << 4) ^ qx7) + ((hi & 1) << 3);
  const int aP2 = (q << 7) + (((4 + (hi >> 1)) << 4) ^ qx7) + ((hi & 1) << 3);
  const int aP3 = (q << 7) + (((6 + (hi >> 1)) << 4) ^ qx7) + ((hi & 1) << 3);

  f32x4 acc[4][4];
#pragma unroll
  for (int mi = 0; mi < 4; ++mi)
#pragma unroll
    for (int ni = 0; ni < 4; ++ni) acc[mi][ni] = z;

  // prologue: V(0) + K(0) -> full drain
#pragma unroll
  for (int j = 0; j < 4; ++j) gload16(vSrcJ[j], sV + ((tid + j * 512) << 4));
  gload16(kSrc, kDst);
  __syncthreads();  // drains vmcnt(0) lgkmcnt(0)

  int cur = 0;
  for (int t = 0; t < 64; ++t) {
    // K(t+1) -> buf^1 (wraps harmlessly at t=63 to keep vmcnt counts uniform)
    gload16(kSrc + (size_t)((t + 1) & 63) * 16384, kDst + (cur ^ 1) * 8192);
    // ---- QK(t): D[s][q], lane owns q=lo; 4 n-blocks x 2 kk
    f32x4 sv[4];
    sv[0] = z; sv[1] = z; sv[2] = z; sv[3] = z;
#pragma unroll
    for (int kk = 0; kk < 2; ++kk) {
#pragma unroll
      for (int n = 0; n < 4; ++n) {
        bf16x8 kf = *(const bf16x8*)(sK + cur * 8192 + swz(n * 16 + lo, kk * 64 + hi * 16));
        sv[n] = __builtin_amdgcn_mfma_f32_16x16x32_bf16(kf, qf[kk], sv[n], 0, 0, 0);
      }
    }
    // ---- exp2 (unnormalized) + l partial + 4x b64 P writes
    {
      const float p0 = __builtin_amdgcn_exp2f(sv[0][0]);
      const float p1 = __builtin_amdgcn_exp2f(sv[0][1]);
      const float p2 = __builtin_amdgcn_exp2f(sv[0][2]);
      const float p3 = __builtin_amdgcn_exp2f(sv[0][3]);
      const float p4 = __builtin_amdgcn_exp2f(sv[1][0]);
      const float p5 = __builtin_amdgcn_exp2f(sv[1][1]);
      const float p6 = __builtin_amdgcn_exp2f(sv[1][2]);
      const float p7 = __builtin_amdgcn_exp2f(sv[1][3]);
      const float p8 = __builtin_amdgcn_exp2f(sv[2][0]);
      const float p9 = __builtin_amdgcn_exp2f(sv[2][1]);
      const float pa_ = __builtin_amdgcn_exp2f(sv[2][2]);
      const float pb_ = __builtin_amdgcn_exp2f(sv[2][3]);
      const float pc_ = __builtin_amdgcn_exp2f(sv[3][0]);
      const float pd_ = __builtin_amdgcn_exp2f(sv[3][1]);
      const float pe_ = __builtin_amdgcn_exp2f(sv[3][2]);
      const float pf_ = __builtin_amdgcn_exp2f(sv[3][3]);
      lsum += (((p0 + p1) + (p2 + p3)) + ((p4 + p5) + (p6 + p7))) +
              (((p8 + p9) + (pa_ + pb_)) + ((pc_ + pd_) + (pe_ + pf_)));
      uint2 d0, d1, d2, d3;
      d0.x = pk_bf16(p0, p1);  d0.y = pk_bf16(p2, p3);
      d1.x = pk_bf16(p4, p5);  d1.y = pk_bf16(p6, p7);
      d2.x = pk_bf16(p8, p9);  d2.y = pk_bf16(pa_, pb_);
      d3.x = pk_bf16(pc_, pd_); d3.y = pk_bf16(pe_, pf_);
      *(uint2*)(sP + aP0) = d0;
      *(uint2*)(sP + aP1) = d1;
      *(uint2*)(sP + aP2) = d2;
      *(uint2*)(sP + aP3) = d3;
    }
    // ---- mid barrier: V(t) gloads landed (vmcnt(1) leaves K(t+1) in flight), P visible
    asm volatile("s_waitcnt vmcnt(1) lgkmcnt(0)" ::: "memory");
    __builtin_amdgcn_sched_barrier(0);
    __builtin_amdgcn_s_barrier();
    __builtin_amdgcn_sched_barrier(0);
    // ---- PV(t): wave (wr,wc), rows wr*64..+64, cols wc*64..+64, k=64 (2 kk halves)
    __builtin_amdgcn_s_setprio(1);
#pragma unroll
    for (int kk = 0; kk < 2; ++kk) {
      bf16x8 pa[4];
#pragma unroll
      for (int mi = 0; mi < 4; ++mi)
        pa[mi] = *(const bf16x8*)(sP + swz(wr * 64 + mi * 16 + lo, kk * 64 + hi * 16));
#pragma unroll
      for (int ni = 0; ni < 4; ++ni) {
        bf16x8 vf = *(const bf16x8*)(sV + swz(wc * 64 + ni * 16 + lo, kk * 64 + hi * 16));
#pragma unroll
        for (int mi = 0; mi < 4; ++mi)
          acc[mi][ni] = __builtin_amdgcn_mfma_f32_16x16x32_bf16(pa[mi], vf, acc[mi][ni], 0, 0, 0);
      }
    }
    __builtin_amdgcn_s_setprio(0);
    __syncthreads();  // all sV/sP reads done; drains K(t+1) (vmcnt 0) + lgkm
    if (t < 63) {     // V(t+1) gloads into the (now fully-read) single buffer
#pragma unroll
      for (int j = 0; j < 4; ++j)
        gload16(vSrcJ[j] + (size_t)(t + 1) * 128, sV + ((tid + j * 512) << 4));
    }
    cur ^= 1;
  }

  // ---- denominator: reduce lsum across the 4 hi-groups, broadcast via LDS
  lsum += __shfl_xor(lsum, 16, 64);
  lsum += __shfl_xor(lsum, 32, 64);
  float* lLds = (float*)smem;   // sK region free after final barrier
  if (hi == 0) lLds[q] = lsum;  // q = w*16+lo covers 0..127 across 8 waves
  __syncthreads();

#pragma unroll
  for (int mi = 0; mi < 4; ++mi)
#pragma unroll
    for (int r = 0; r < 4; ++r) {
      const int rloc = wr * 64 + mi * 16 + hi * 4 + r;
      const int grow = (int)qrow0 + rloc;
      const float linv = 1.0f / lLds[rloc];  // same addr for 16 lanes -> broadcast
#pragma unroll
      for (int ni = 0; ni < 4; ++ni) {
        const int col = ck * 256 + wc * 64 + ni * 16 + lo;
        out[(size_t)grow * 1024 + col] = acc[mi][ni][r] * linv;
      }
    }
}

// ---------------------------------------------------------------- launch
extern "C" void kernel_launch(void* const* d_in, const int* in_sizes, int n_in,
                              void* d_out, int out_size, void* d_ws, size_t ws_size,
                              hipStream_t stream) {
  const float* x  = (const float*)d_in[0];
  const float* Wq = (const float*)d_in[1];
  const float* Wk = (const float*)d_in[2];
  const float* Wv = (const float*)d_in[3];

  char* ws = (char*)d_ws;
  unsigned short* xb    = (unsigned short*)(ws);               // 33,554,432 B
  unsigned short* wcat  = (unsigned short*)(ws + 33554432);    //  2,359,296 B
  unsigned short* qk    = (unsigned short*)(ws + 35913728);    //  4,194,304 B
  unsigned short* vT    = (unsigned short*)(ws + 40108032);    // 33,554,432 B

  const float SCALE_Q = 0.125f * 1.4426950408889634f;  // fold softmax scale+log2e into Wq

  cast_all_k<<<2048, 256, 0, stream>>>(x, Wq, Wk, Wv, xb, wcat, SCALE_Q);
  gemm_qkv_k<<<dim3(9, 128), 256, 0, stream>>>(xb, wcat, qk, vT);
  pv_k<<<dim3(4, 32, 4), 512, 0, stream>>>(qk, vT, (float*)d_out);
}